// Round 1
// baseline (90.040 us; speedup 1.0000x reference)
//
#include <hip/hip_runtime.h>
#include <hip/hip_bf16.h>
#include <math.h>

// Problem: BoundaryDistanceLoss — H=W=1024 binary masks (float 0/1).
// edges = seg - erode3x3(seg); exact EDT of edges; loss =
// sigmoid((mean(target_edges*pred_dt) + mean(pred_edges*target_dt))/2).
//
// ws layout: hp (4MB) | ht (4MB) | ep (1MB u8) | et (1MB u8) | acc (4B)
// h[k][j] = g2[k][j] + k^2   (g2 = squared row-pass distance)

#define HW 1024
#define BIGF 1e6f
#define RMIN_SENT (1 << 30)

// ---------------- Kernel A: edges + row-pass (per row) ----------------
__global__ __launch_bounds__(256)
void k_rows(const float* __restrict__ pred, const float* __restrict__ targ,
            float* __restrict__ hp, float* __restrict__ ht,
            unsigned char* __restrict__ ep, unsigned char* __restrict__ et,
            float* __restrict__ acc)
{
    const int r = blockIdx.x;      // row 0..1023
    const int m = blockIdx.y;      // image 0=pred 1=target
    const int t = threadIdx.x;     // 0..255
    const float* __restrict__ seg = m ? targ : pred;
    float* __restrict__ hout = m ? ht : hp;
    unsigned char* __restrict__ eout = m ? et : ep;

    if (r == 0 && m == 0 && t == 0) acc[0] = 0.f;  // kernel B runs after A completes

    __shared__ unsigned char colall[HW];
    __shared__ int scanL[256];
    __shared__ int scanR[256];

    const int j4 = t * 4;
    // load own 4 columns of rows r-1, r, r+1 (zero padding outside)
    float4 c0 = *(const float4*)&seg[r * HW + j4];
    float4 cm = make_float4(0.f, 0.f, 0.f, 0.f);
    float4 cp = make_float4(0.f, 0.f, 0.f, 0.f);
    if (r > 0)        cm = *(const float4*)&seg[(r - 1) * HW + j4];
    if (r < HW - 1)   cp = *(const float4*)&seg[(r + 1) * HW + j4];

    const float s0v[4] = {c0.x, c0.y, c0.z, c0.w};
    const float smv[4] = {cm.x, cm.y, cm.z, cm.w};
    const float spv[4] = {cp.x, cp.y, cp.z, cp.w};

    unsigned char ca[4];
    #pragma unroll
    for (int u = 0; u < 4; ++u)
        ca[u] = (s0v[u] != 0.f && smv[u] != 0.f && spv[u] != 0.f) ? 1 : 0;
    *(uchar4*)&colall[j4] = make_uchar4(ca[0], ca[1], ca[2], ca[3]);
    __syncthreads();

    // eroded = 3x3 all-ones (zero padding) ; edge = seg && !eroded
    int lmax = -1, rmin = RMIN_SENT;
    unsigned char fe[4];
    #pragma unroll
    for (int u = 0; u < 4; ++u) {
        const int j = j4 + u;
        int er = 0;
        if (j > 0 && j < HW - 1)
            er = colall[j - 1] & ca[u] & colall[j + 1];
        const int e = (s0v[u] != 0.f) && !er;
        fe[u] = (unsigned char)e;
        if (e) { lmax = j; if (rmin == RMIN_SENT) rmin = j; }
    }
    *(uchar4*)&eout[r * HW + j4] = make_uchar4(fe[0], fe[1], fe[2], fe[3]);

    // block scans over 256 thread-partials (max from left, min from right)
    scanL[t] = lmax;
    scanR[t] = rmin;
    __syncthreads();
    for (int off = 1; off < 256; off <<= 1) {
        const int vl = (t >= off) ? scanL[t - off] : -1;
        const int vr = (t + off < 256) ? scanR[t + off] : RMIN_SENT;
        __syncthreads();
        scanL[t] = max(scanL[t], vl);
        scanR[t] = min(scanR[t], vr);
        __syncthreads();
    }
    const int carryL = (t > 0) ? scanL[t - 1] : -1;
    const int carryR = (t < 255) ? scanR[t + 1] : RMIN_SENT;

    int Lv[4], Rv[4];
    {
        int L = carryL;
        #pragma unroll
        for (int u = 0; u < 4; ++u) { if (fe[u]) L = j4 + u; Lv[u] = L; }
    }
    {
        int R = carryR;
        #pragma unroll
        for (int u = 3; u >= 0; --u) { if (fe[u]) R = j4 + u; Rv[u] = R; }
    }

    const float rr = (float)(r * r);
    float hv[4];
    #pragma unroll
    for (int u = 0; u < 4; ++u) {
        const float jf = (float)(j4 + u);
        const float left  = jf - ((Lv[u] < 0) ? -BIGF : (float)Lv[u]);
        const float right = ((Rv[u] >= RMIN_SENT) ? BIGF : (float)Rv[u]) - jf;
        float g = fminf(fminf(left, right), BIGF);
        hv[u] = g * g + rr;
    }
    float4 ho; ho.x = hv[0]; ho.y = hv[1]; ho.z = hv[2]; ho.w = hv[3];
    *(float4*)&hout[r * HW + j4] = ho;
}

// ------------- Kernel B: column EDT (windowed, exact) + weighted sum -------------
// grid (64 col-tiles, 4 row-chunks, 2 images), block 256.
// Block covers cols [j0,j0+16), output rows [i0,i0+256). LDS stages
// h rows [i0-32, i0+288) (OOB filled +inf) with stride-17 padding.
#define WIN 32
#define KROWS 320          // 256 + 2*WIN
#define HS_STRIDE 17

__global__ __launch_bounds__(256)
void k_cols(const float* __restrict__ hp, const float* __restrict__ ht,
            const unsigned char* __restrict__ ep, const unsigned char* __restrict__ et,
            float* __restrict__ acc)
{
    const int j0 = blockIdx.x * 16;
    const int i0 = blockIdx.y * 256;
    const int m  = blockIdx.z;
    const float* __restrict__ hg = m ? ht : hp;
    const unsigned char* __restrict__ ew = m ? ep : et;  // weight = OTHER image's edges

    __shared__ float hs[KROWS * HS_STRIDE];
    __shared__ alignas(16) unsigned char es[256 * 16];
    __shared__ float wsum[4];

    for (int idx = threadIdx.x; idx < KROWS * 16; idx += 256) {
        const int kk = idx >> 4, jc = idx & 15;
        const int gk = i0 - WIN + kk;
        float v = 1e30f;
        if ((unsigned)gk < (unsigned)HW) v = hg[gk * HW + j0 + jc];
        hs[kk * HS_STRIDE + jc] = v;
    }
    // stage weight edges tile (16B per row, coalesced)
    *(uint4*)&es[threadIdx.x * 16] = *(const uint4*)&ew[(i0 + threadIdx.x) * HW + j0];
    __syncthreads();

    const int jj = threadIdx.x & 15;
    const int iw = threadIdx.x >> 4;   // 0..15, each owns 16 rows
    float lsum = 0.f;

    #pragma unroll
    for (int g = 0; g < 4; ++g) {
        const int ib = i0 + iw * 16 + g * 4;     // 4 consecutive output rows
        const int kkS = iw * 16 + g * 4;         // = (ib-WIN) - (i0-WIN)
        float b0 = 3e38f, b1 = 3e38f, b2 = 3e38f, b3 = 3e38f;
        float kf = (float)(ib - WIN);
        const float m0 = -2.f * (float)(ib);
        const float m1 = -2.f * (float)(ib + 1);
        const float m2 = -2.f * (float)(ib + 2);
        const float m3 = -2.f * (float)(ib + 3);
        #pragma unroll 4
        for (int kk = kkS; kk < kkS + 2 * WIN + 4; ++kk) {
            const float hvv = hs[kk * HS_STRIDE + jj];
            b0 = fminf(b0, fmaf(m0, kf, hvv));
            b1 = fminf(b1, fmaf(m1, kf, hvv));
            b2 = fminf(b2, fmaf(m2, kf, hvv));
            b3 = fminf(b3, fmaf(m3, kf, hvv));
            kf += 1.f;
        }
        const int sLo = max(0, ib - WIN);
        const int sHi = min(HW - 1, ib + WIN + 3);
        float bs[4] = {b0, b1, b2, b3};
        #pragma unroll
        for (int w = 0; w < 4; ++w) {
            const int i = ib + w;
            float D2 = (float)(i * i) + bs[w];
            // exactness check: any excluded k has (i-k)^2 >= gap^2
            const int dl = i - sLo + 1, dr = sHi + 1 - i;
            const bool need = ((sLo > 0) && (D2 > (float)(dl * dl))) ||
                              ((sHi < HW - 1) && (D2 > (float)(dr * dr)));
            if (need) {  // rare exact fallback: full column scan from global
                float bb = 3e38f, k2 = 0.f;
                const float mm = -2.f * (float)i;
                for (int k = 0; k < HW; ++k) {
                    bb = fminf(bb, fmaf(mm, k2, hg[k * HW + j0 + jj]));
                    k2 += 1.f;
                }
                D2 = (float)(i * i) + bb;
            }
            if (es[(i - i0) * 16 + jj]) lsum += sqrtf(D2);
        }
    }

    // reduce: wave shuffle then cross-wave via LDS, one atomic per block
    #pragma unroll
    for (int off = 32; off > 0; off >>= 1) lsum += __shfl_down(lsum, off);
    if ((threadIdx.x & 63) == 0) wsum[threadIdx.x >> 6] = lsum;
    __syncthreads();
    if (threadIdx.x == 0)
        atomicAdd(acc, wsum[0] + wsum[1] + wsum[2] + wsum[3]);
}

// ---------------- Kernel C: finalize ----------------
__global__ void k_fin(const float* __restrict__ acc, float* __restrict__ out)
{
    const float loss = acc[0] * (1.f / (2.f * 1024.f * 1024.f));
    out[0] = 1.f / (1.f + expf(-loss));
}

extern "C" void kernel_launch(void* const* d_in, const int* in_sizes, int n_in,
                              void* d_out, int out_size, void* d_ws, size_t ws_size,
                              hipStream_t stream)
{
    const float* preds   = (const float*)d_in[0];
    const float* targets = (const float*)d_in[1];
    float* out = (float*)d_out;

    char* ws = (char*)d_ws;
    float* hp = (float*)ws;                               // 4 MB
    float* ht = hp + HW * HW;                             // 4 MB
    unsigned char* ep = (unsigned char*)(ht + HW * HW);   // 1 MB
    unsigned char* et = ep + HW * HW;                     // 1 MB
    float* acc = (float*)(et + HW * HW);                  // 4 B

    dim3 gA(HW, 2, 1);
    k_rows<<<gA, 256, 0, stream>>>(preds, targets, hp, ht, ep, et, acc);

    dim3 gB(HW / 16, HW / 256, 2);
    k_cols<<<gB, 256, 0, stream>>>(hp, ht, ep, et, acc);

    k_fin<<<1, 1, 0, stream>>>(acc, out);
}